// Round 16
// baseline (3039.861 us; speedup 1.0000x reference)
//
#include <hip/hip_runtime.h>
#include <math.h>
#include <float.h>

namespace {

constexpr int Bb = 8, Kk = 4, BKn = 32, Dd = 1024, Ff = 4096, Vv = 32000, Tt = 16;
constexpr int GDS = 32, GDC = 32;        // gates d-split / d-chunk  (32*32 = 1024)
constexpr int LTW = 64;                  // logits cols per block
constexpr int LNB = Vv / LTW;            // 500 blocks
constexpr int LCH = 32;                  // d per chunk
constexpr int LNCH = 32;                 // chunks (32*32 = 1024 d)
constexpr int NVCH = LNB;                // 500 chunk-stat rows
constexpr int EOSt = 2, PADt = 0;
constexpr float BIGf = 1e9f, EOSSf = 1000.0f;

// ---- workspace layout (float indices) ----
constexpr size_t OFF_HTN = 0;                                   // hTn [1024][32]
constexpr size_t OFF_CB0 = OFF_HTN + (size_t)Dd * BKn;          // c ping [32][1024]
constexpr size_t OFF_CB1 = OFF_CB0 + (size_t)BKn * Dd;          // c pong
constexpr size_t OFF_GP  = OFF_CB1 + (size_t)BKn * Dd;          // gate partials [32][32][4096]
constexpr size_t OFF_CS  = OFF_GP  + (size_t)GDS * BKn * Ff;    // chunk stats [500][32][12]
constexpr size_t OFF_SC  = OFF_CS  + (size_t)NVCH * BKn * 12;   // scores [32]
constexpr size_t OFF_INT = OFF_SC  + BKn;                       // int region
constexpr int IW = 0, ISTOP = 32, IPREV = 40, IBUFA = 72, IBUFB = IBUFA + Bb * Kk * Tt;

__device__ __forceinline__ void cp16(const float* g, float* l) {
  __builtin_amdgcn_global_load_lds(
      (const __attribute__((address_space(1))) void*)g,
      (__attribute__((address_space(3))) void*)l, 16, 0, 0);
}

__device__ inline void ins4(float v, int id, float tv[4], int ti[4]) {
#pragma unroll
  for (int r = 0; r < 4; r++) {
    bool better = (v > tv[r]) || (v == tv[r] && id < ti[r]);
    if (better) { float fv = tv[r]; int fi = ti[r]; tv[r] = v; ti[r] = id; v = fv; id = fi; }
  }
}

// merge per-lane sorted top-4 into group-global top-4. STARTOFF=32 -> 64-lane wave,
// STARTOFF=16 -> independent 32-lane halves.
template <int STARTOFF>
__device__ inline void merge_top4(float tv[4], int ti[4], float ov[4], int oi[4]) {
#pragma unroll
  for (int r = 0; r < 4; r++) {
    float hv = tv[0]; int hi = ti[0];
    float m = hv;
    for (int off = STARTOFF; off; off >>= 1) m = fmaxf(m, __shfl_xor(m, off));
    int c = (hv == m) ? hi : 0x7fffffff;
    for (int off = STARTOFF; off; off >>= 1) c = min(c, __shfl_xor(c, off));
    if (hv == m && hi == c) {   // this lane's head won: pop
      tv[0] = tv[1]; ti[0] = ti[1];
      tv[1] = tv[2]; ti[1] = ti[2];
      tv[2] = tv[3]; ti[2] = ti[3];
      tv[3] = -FLT_MAX; ti[3] = 0x7fffffff;
    }
    ov[r] = m; oi[r] = c;
  }
}

__global__ __launch_bounds__(256) void initK(const int* __restrict__ words,
    const float* __restrict__ h0, const float* __restrict__ c0,
    float* __restrict__ ws) {
  int* wsi = (int*)(ws + OFF_INT);
  if (blockIdx.x < 128) {
    int g = blockIdx.x * 256 + threadIdx.x;   // 0..32767
    int d = g >> 5, bk = g & 31;
    ws[OFF_HTN + g] = h0[(size_t)bk * Dd + d];   // transpose to [d][bk]
    ws[OFF_CB0 + g] = c0[g];                     // [32][1024] linear
  } else {
    int t = threadIdx.x;
    if (t < BKn) {
      ws[OFF_SC + t] = ((t & 3) == 0) ? 0.f : BIGf;
      wsi[IW + t] = words[t];
      wsi[IPREV + t] = t & 3;                    // identity gather for step 0
    }
    if (t < Bb) wsi[ISTOP + t] = 0;
    for (int i = t; i < 2 * Bb * Kk * Tt; i += 256) wsi[IBUFA + i] = 0;
  }
}

// gates partial GEMM. grid (32, 32): x = 128-col tile of f, y = d-chunk of 32.
__global__ __launch_bounds__(256) void gatesK(const float* __restrict__ Wx,
    const float* __restrict__ Wh, const float* __restrict__ E,
    const float* __restrict__ hTn, const int* __restrict__ wsi,
    float* __restrict__ Gp) {
  __shared__ float xs[GDC][BKn], hs[GDC][BKn];
  int tid = threadIdx.x;
  int d0 = blockIdx.y * GDC;
  {
    int bk = tid & 31, dq = tid >> 5;           // dq 0..7, 4 d each
    int w = wsi[IW + bk];
    int src = (bk & ~3) | wsi[IPREV + bk];
    const float* Erow = E + (size_t)w * Dd + d0;
#pragma unroll
    for (int k = 0; k < 4; k++) {
      int d = dq * 4 + k;
      xs[d][bk] = Erow[d];
      hs[d][bk] = hTn[(size_t)(d0 + d) * BKn + src];
    }
  }
  __syncthreads();
  int ct = tid & 31, bg = tid >> 5;             // 32 col-threads, 8 beam-groups
  int f0 = blockIdx.x * 128 + ct * 4;
  float acc[4][4];                               // [col][beam-in-group]
#pragma unroll
  for (int c = 0; c < 4; c++)
#pragma unroll
    for (int i = 0; i < 4; i++) acc[c][i] = 0.f;
#pragma unroll 4
  for (int d = 0; d < GDC; ++d) {
    float4 wx = *(const float4*)(Wx + (size_t)(d0 + d) * Ff + f0);
    float4 wh = *(const float4*)(Wh + (size_t)(d0 + d) * Ff + f0);
    float4 x4 = *(const float4*)&xs[d][bg * 4];
    float4 h4 = *(const float4*)&hs[d][bg * 4];
    float xv[4] = {x4.x, x4.y, x4.z, x4.w};
    float hv[4] = {h4.x, h4.y, h4.z, h4.w};
    float wxc[4] = {wx.x, wx.y, wx.z, wx.w};
    float whc[4] = {wh.x, wh.y, wh.z, wh.w};
#pragma unroll
    for (int c = 0; c < 4; c++)
#pragma unroll
      for (int i = 0; i < 4; i++)
        acc[c][i] = fmaf(xv[i], wxc[c], fmaf(hv[i], whc[c], acc[c][i]));
  }
#pragma unroll
  for (int i = 0; i < 4; i++) {
    int bk = bg * 4 + i;
    float4 o = {acc[0][i], acc[1][i], acc[2][i], acc[3][i]};
    *(float4*)(Gp + ((size_t)blockIdx.y * BKn + bk) * Ff + f0) = o;
  }
}

// reduce 32 gate partials + bias -> nonlinearity; gathers c by prev.
__global__ __launch_bounds__(256) void lstmK(const float* __restrict__ bvec,
    const float* __restrict__ Gp, const float* __restrict__ cPrev,
    const int* __restrict__ wsi, float* __restrict__ cNew,
    float* __restrict__ hTn) {
  __shared__ float part[4][128];
  int bk = blockIdx.x;
  int dcl = threadIdx.x & 127;
  int half = threadIdx.x >> 7;
  int dc = blockIdx.y * 128 + dcl;
  float s[4] = {0.f, 0.f, 0.f, 0.f};
#pragma unroll 4
  for (int dsl = 0; dsl < 16; dsl++) {
    int ds = half * 16 + dsl;
    const float* row = Gp + ((size_t)ds * BKn + bk) * Ff;
#pragma unroll
    for (int g = 0; g < 4; g++) s[g] += row[(size_t)g * Dd + dc];
  }
  if (half == 1) {
#pragma unroll
    for (int g = 0; g < 4; g++) part[g][dcl] = s[g];
  }
  __syncthreads();
  if (half == 0) {
    float gi = s[0] + part[0][dcl] + bvec[dc];
    float gf = s[1] + part[1][dcl] + bvec[Dd + dc];
    float gg = s[2] + part[2][dcl] + bvec[2 * Dd + dc];
    float go = s[3] + part[3][dcl] + bvec[3 * Dd + dc];
    int src = (bk & ~3) | wsi[IPREV + bk];
    float c = cPrev[(size_t)src * Dd + dc];
    float si = 1.f / (1.f + expf(-gi));
    float sf = 1.f / (1.f + expf(-gf));
    float so = 1.f / (1.f + expf(-go));
    float tg = tanhf(gg);
    float cn = sf * c + si * tg;
    float hn = so * tanhf(cn);
    cNew[(size_t)bk * Dd + dc] = cn;
    hTn[(size_t)dc * BKn + bk] = hn;
  }
}

// Barrierless 1-wave logits + chunk stats. grid 500 blocks x 64 thr (ONE wave).
// Block = 64 vocab cols x all 1024 d, 32 chunks of 32 d, triple-buffered
// depth-2 DMA (12 cp16/chunk, steady vmcnt(24)). No s_barrier anywhere:
// per-wave vmcnt is the only sync, so no inter-wave convoy. Thread tile
// 8 cols x 4 beams = 48B LDS per 32 FMA (1.5 B/FMA, 25% less than R12).
// LDS 44 KB -> 3 blocks/CU.
__global__ __launch_bounds__(64) void logitsAK(const float* __restrict__ Wo,
    const float* __restrict__ bo, const float* __restrict__ hTn,
    float* __restrict__ cs) {
  __shared__ float wb[3][LCH][LTW];   // 24 KB
  __shared__ float hb[3][LCH][BKn];   // 12 KB
  __shared__ float sd[BKn][LTW];      // 8 KB
  int t = threadIdx.x;                // lane 0..63
  int cg = t & 7;                     // col group (8 cols)
  int bg = t >> 3;                    // beam group (4 beams), 0..7
  size_t v0 = (size_t)blockIdx.x * LTW;
  float acc[8][4];                    // [col][beam]
#pragma unroll
  for (int c = 0; c < 8; c++)
#pragma unroll
    for (int i = 0; i < 4; i++) acc[c][i] = 0.f;

  // bias: issued first (drains before chunk 0's wait)
  float4 b4a = *(const float4*)(bo + v0 + cg * 8);
  float4 b4b = *(const float4*)(bo + v0 + cg * 8 + 4);

  // stage chunk CH into buf B: 8 Wo cp16 (4 rows each) + 4 h cp16 (8 rows each)
#define STAGE(CH, B)                                                          \
  {                                                                           \
    int d0_ = (CH) * LCH;                                                     \
    _Pragma("unroll") for (int k_ = 0; k_ < 8; k_++)                          \
      cp16(Wo + (size_t)(d0_ + k_ * 4 + (t >> 4)) * Vv + v0 + (t & 15) * 4,   \
           &wb[B][k_ * 4][0]);                                                \
    _Pragma("unroll") for (int k_ = 0; k_ < 4; k_++)                          \
      cp16(hTn + (size_t)(d0_ + k_ * 8 + (t >> 3)) * BKn + (t & 7) * 4,       \
           &hb[B][k_ * 8][0]);                                                \
  }

  STAGE(0, 0)
  STAGE(1, 1)
  for (int k = 0; k < LNCH; k++) {
    int b = k % 3;
    if (k + 2 < LNCH) {
      STAGE(k + 2, (k + 2) % 3)
      asm volatile("s_waitcnt vmcnt(24)" ::: "memory");  // chunk k landed
    } else if (k + 1 < LNCH) {
      asm volatile("s_waitcnt vmcnt(12)" ::: "memory");
    } else {
      asm volatile("s_waitcnt vmcnt(0)" ::: "memory");
    }
#pragma unroll 8
    for (int d = 0; d < LCH; d++) {
      float4 wlo = *(const float4*)&wb[b][d][cg * 8];
      float4 whi = *(const float4*)&wb[b][d][cg * 8 + 4];
      float4 h4  = *(const float4*)&hb[b][d][bg * 4];
      float wv[8] = {wlo.x, wlo.y, wlo.z, wlo.w, whi.x, whi.y, whi.z, whi.w};
      float hv[4] = {h4.x, h4.y, h4.z, h4.w};
#pragma unroll
      for (int c = 0; c < 8; c++)
#pragma unroll
        for (int i = 0; i < 4; i++)
          acc[c][i] = fmaf(wv[c], hv[i], acc[c][i]);
    }
    // no barrier: single wave, vmcnt governs buffer reuse (depth-2 spacing)
  }
#undef STAGE

  // bias + stash logits in sd (same wave; compiler orders LDS ops)
  float bb[8] = {b4a.x, b4a.y, b4a.z, b4a.w, b4b.x, b4b.y, b4b.z, b4b.w};
#pragma unroll
  for (int c = 0; c < 8; c++)
#pragma unroll
    for (int i = 0; i < 4; i++)
      sd[bg * 4 + i][cg * 8 + c] = acc[c][i] + bb[c];

  // stats: one wave sweeps all 32 beams over its 64 cols
  int i0 = (int)v0 + t;
  for (int bk = 0; bk < BKn; ++bk) {
    float v0f = sd[bk][t];
    float m = v0f;
    for (int off = 32; off; off >>= 1) m = fmaxf(m, __shfl_xor(m, off));
    float se = expf(v0f - m);
    for (int off = 32; off; off >>= 1) se += __shfl_xor(se, off);
    float tv[4]; int ti[4];
#pragma unroll
    for (int r = 0; r < 4; r++) { tv[r] = -FLT_MAX; ti[r] = 0x7fffffff; }
    ins4(v0f, i0, tv, ti);
    float ov[4]; int oi[4];
    merge_top4<32>(tv, ti, ov, oi);
    if (t == 0) {
      float* p = cs + ((size_t)blockIdx.x * BKn + bk) * 12;
      p[0] = m; p[1] = se;
#pragma unroll
      for (int r = 0; r < 4; r++) { p[2 + r] = ov[r]; p[6 + r] = __int_as_float(oi[r]); }
    }
  }
}

// fused: per-beam online merge of 500 chunk stats -> lse + top4; then exact
// selection, EOS logic, buf ping-pong. One block of 1024 threads.
// Loads batched in groups of 4 chunks via explicit float4 register arrays.
__global__ __launch_bounds__(1024) void redSelK(float* __restrict__ ws, int step) {
  __shared__ float bt_s[BKn][8];
  __shared__ int s_tok[BKn], s_prevb[BKn];
  int* wsi = (int*)(ws + OFF_INT);
  const float* cs = ws + OFF_CS;
  int tid = threadIdx.x;
  int wv = tid >> 6, lane = tid & 63;
  {
    int half = lane >> 5, l32 = lane & 31;
    int bk = wv * 2 + half;                 // 16 waves x 2 halves = 32 beams
    float tv[4]; int ti[4];
#pragma unroll
    for (int r = 0; r < 4; r++) { tv[r] = -FLT_MAX; ti[r] = 0x7fffffff; }
    float M = -FLT_MAX, ls = 0.f;
    for (int g = 0; g < 4; g++) {           // 4 groups x 4 chunks = 16 chunks/lane
      float4 pa[4], pb[4], pc[4];
      bool vv[4];
#pragma unroll
      for (int j = 0; j < 4; j++) {
        int c = l32 + 32 * (g * 4 + j);
        vv[j] = c < NVCH;
        const float* p = cs + ((size_t)c * BKn + bk) * 12;
        if (vv[j]) {
          pa[j] = *(const float4*)p;        // {m, se, ov0, ov1}
          pb[j] = *(const float4*)(p + 4);  // {ov2, ov3, oi0, oi1}
          pc[j] = *(const float4*)(p + 8);  // {oi2, oi3, -, -}
        }
      }
#pragma unroll
      for (int j = 0; j < 4; j++) {
        if (vv[j]) {
          float cm = pa[j].x, csum = pa[j].y;
          if (cm > M) { ls *= expf(M - cm); M = cm; }   // ls==0 when M==-inf
          ls += csum * expf(cm - M);
          ins4(pa[j].z, __float_as_int(pb[j].z), tv, ti);
          ins4(pa[j].w, __float_as_int(pb[j].w), tv, ti);
          ins4(pb[j].x, __float_as_int(pc[j].x), tv, ti);
          ins4(pb[j].y, __float_as_int(pc[j].y), tv, ti);
        }
      }
    }
    for (int off = 16; off; off >>= 1) {
      float Mo = __shfl_xor(M, off), lso = __shfl_xor(ls, off);
      float Mn = fmaxf(M, Mo);
      ls = ls * expf(M - Mn) + lso * expf(Mo - Mn);
      M = Mn;
    }
    float lse = M + logf(ls);
    float ov[4]; int oi[4];
    merge_top4<16>(tv, ti, ov, oi);
    if (l32 == 0) {
#pragma unroll
      for (int r = 0; r < 4; r++) {
        bt_s[bk][r] = lse - ov[r];
        bt_s[bk][4 + r] = __int_as_float(oi[r]);
      }
    }
  }
  __syncthreads();
  if (tid < Bb) {
    int b = tid;
    int st = wsi[ISTOP + b];
    float sc[4];
#pragma unroll
    for (int k = 0; k < 4; k++) sc[k] = ws[OFF_SC + b * 4 + k];
    float cval[16]; int ctok[16];
#pragma unroll
    for (int kb = 0; kb < 4; kb++)
#pragma unroll
      for (int r = 0; r < 4; r++) {
        cval[kb * 4 + r] = bt_s[b * 4 + kb][r] + sc[kb];
        ctok[kb * 4 + r] = __float_as_int(bt_s[b * 4 + kb][4 + r]);
      }
    float selS[4]; int selW[4], prevK[4];
    int usedMask = 0;
#pragma unroll
    for (int r = 0; r < 4; r++) {
      int best = -1; float bv = FLT_MAX;
#pragma unroll
      for (int t = 0; t < 16; t++) {
        if (!((usedMask >> t) & 1) && cval[t] < bv) { bv = cval[t]; best = t; }
      }
      usedMask |= 1 << best;
      int tok = 0;
#pragma unroll
      for (int t = 0; t < 16; t++) if (t == best) tok = ctok[t];   // no runtime index
      selS[r] = bv; selW[r] = tok; prevK[r] = best >> 2;
    }
    bool eos[4];
#pragma unroll
    for (int r = 0; r < 4; r++) eos[r] = (selW[r] == EOSt);
    bool first = eos[0] && !st;
#pragma unroll
    for (int r = 0; r < 4; r++) if (eos[r] && !first && !st) selS[r] = EOSSf;
#pragma unroll
    for (int k = 0; k < 4; k++) {
      int tok = st ? PADt : (first ? EOSt : selW[k]);
      int pb  = st ? k : prevK[k];
      s_tok[b * 4 + k] = tok;
      s_prevb[b * 4 + k] = pb;
      if (!st) { ws[OFF_SC + b * 4 + k] = selS[k]; wsi[IW + b * 4 + k] = selW[k]; }
      wsi[IPREV + b * 4 + k] = prevK[k];
    }
    wsi[ISTOP + b] = (st || first) ? 1 : 0;
  }
  __syncthreads();
  if (tid < 512) {
    const int* br = wsi + (((step & 1) == 0) ? IBUFA : IBUFB);
    int* bw = wsi + (((step & 1) == 0) ? IBUFB : IBUFA);
    int bkk = tid >> 4, t = tid & 15;
    int pb = s_prevb[bkk];
    int src = ((bkk & ~3) | pb) * Tt + t;
    int val = br[src];
    if (t == step) val = s_tok[bkk];
    bw[tid] = val;
  }
}

// Output read as float32 by harness: tokens as float values, scores as floats.
__global__ __launch_bounds__(256) void outK(const float* __restrict__ ws,
                                            float* __restrict__ out) {
  const int* wsi = (const int*)(ws + OFF_INT);
  int g = blockIdx.x * 256 + threadIdx.x;
  if (g < Bb * Kk * Tt) {
    out[g] = (float)wsi[IBUFA + g];               // final buf in A after 16 steps
  } else if (g < Bb * Kk * Tt + BKn) {
    out[g] = ws[OFF_SC + (g - Bb * Kk * Tt)];
  }
}

} // namespace

extern "C" void kernel_launch(void* const* d_in, const int* in_sizes, int n_in,
                              void* d_out, int out_size, void* d_ws, size_t ws_size,
                              hipStream_t stream) {
  (void)in_sizes; (void)n_in; (void)out_size; (void)ws_size;
  const int*   words = (const int*)d_in[0];
  const float* h0 = (const float*)d_in[1];
  const float* c0 = (const float*)d_in[2];
  const float* E  = (const float*)d_in[3];
  const float* Wx = (const float*)d_in[4];
  const float* Wh = (const float*)d_in[5];
  const float* bv = (const float*)d_in[6];
  const float* Wo = (const float*)d_in[7];
  const float* bo = (const float*)d_in[8];
  float* ws = (float*)d_ws;
  float* hTn = ws + OFF_HTN;
  float* cb0 = ws + OFF_CB0;
  float* cb1 = ws + OFF_CB1;
  float* Gp  = ws + OFF_GP;
  float* cs  = ws + OFF_CS;
  int*   wsi = (int*)(ws + OFF_INT);

  initK<<<129, 256, 0, stream>>>(words, h0, c0, ws);
  for (int j = 0; j < Tt; j++) {
    float* cPrev = (j & 1) ? cb1 : cb0;
    float* cNext = (j & 1) ? cb0 : cb1;
    gatesK<<<dim3(32, GDS), 256, 0, stream>>>(Wx, Wh, E, hTn, wsi, Gp);
    lstmK<<<dim3(32, 8), 256, 0, stream>>>(bv, Gp, cPrev, wsi, cNext, hTn);
    logitsAK<<<LNB, 64, 0, stream>>>(Wo, bo, hTn, cs);
    redSelK<<<1, 1024, 0, stream>>>(ws, j);
  }
  outK<<<3, 256, 0, stream>>>(ws, (float*)d_out);
}

// Round 18
// 1728.501 us; speedup vs baseline: 1.7587x; 1.7587x over previous
//
#include <hip/hip_runtime.h>
#include <math.h>
#include <float.h>

namespace {

constexpr int Bb = 8, Kk = 4, BKn = 32, Dd = 1024, Ff = 4096, Vv = 32000, Tt = 16;
constexpr int GDS = 32, GDC = 32;        // gates d-split / d-chunk  (32*32 = 1024)
constexpr int LTW = 64;                  // logits cols per block
constexpr int LNB = Vv / LTW;            // 500 blocks
constexpr int LQC = 16;                  // d per chunk (per quarter)
constexpr int LQN = 16;                  // chunks per quarter (16*16 = 256 d)
constexpr int NVCH = LNB;                // 500 chunk-stat rows
constexpr int EOSt = 2, PADt = 0;
constexpr float BIGf = 1e9f, EOSSf = 1000.0f;

// ---- workspace layout (float indices) ----
constexpr size_t OFF_HTN = 0;                                   // hTn [1024][32]
constexpr size_t OFF_CB0 = OFF_HTN + (size_t)Dd * BKn;          // c ping [32][1024]
constexpr size_t OFF_CB1 = OFF_CB0 + (size_t)BKn * Dd;          // c pong
constexpr size_t OFF_GP  = OFF_CB1 + (size_t)BKn * Dd;          // gate partials [32][32][4096]
constexpr size_t OFF_CS  = OFF_GP  + (size_t)GDS * BKn * Ff;    // chunk stats [500][32][12]
constexpr size_t OFF_SC  = OFF_CS  + (size_t)NVCH * BKn * 12;   // scores [32]
constexpr size_t OFF_INT = OFF_SC  + BKn;                       // int region
constexpr int IW = 0, ISTOP = 32, IPREV = 40, IBUFA = 72, IBUFB = IBUFA + Bb * Kk * Tt;

__device__ __forceinline__ void cp16(const float* g, float* l) {
  __builtin_amdgcn_global_load_lds(
      (const __attribute__((address_space(1))) void*)g,
      (__attribute__((address_space(3))) void*)l, 16, 0, 0);
}

__device__ inline void ins4(float v, int id, float tv[4], int ti[4]) {
#pragma unroll
  for (int r = 0; r < 4; r++) {
    bool better = (v > tv[r]) || (v == tv[r] && id < ti[r]);
    if (better) { float fv = tv[r]; int fi = ti[r]; tv[r] = v; ti[r] = id; v = fv; id = fi; }
  }
}

// merge per-lane sorted top-4 into group-global top-4. STARTOFF=32 -> 64-lane wave,
// STARTOFF=16 -> independent 32-lane halves.
template <int STARTOFF>
__device__ inline void merge_top4(float tv[4], int ti[4], float ov[4], int oi[4]) {
#pragma unroll
  for (int r = 0; r < 4; r++) {
    float hv = tv[0]; int hi = ti[0];
    float m = hv;
    for (int off = STARTOFF; off; off >>= 1) m = fmaxf(m, __shfl_xor(m, off));
    int c = (hv == m) ? hi : 0x7fffffff;
    for (int off = STARTOFF; off; off >>= 1) c = min(c, __shfl_xor(c, off));
    if (hv == m && hi == c) {   // this lane's head won: pop
      tv[0] = tv[1]; ti[0] = ti[1];
      tv[1] = tv[2]; ti[1] = ti[2];
      tv[2] = tv[3]; ti[2] = ti[3];
      tv[3] = -FLT_MAX; ti[3] = 0x7fffffff;
    }
    ov[r] = m; oi[r] = c;
  }
}

__global__ __launch_bounds__(256) void initK(const int* __restrict__ words,
    const float* __restrict__ h0, const float* __restrict__ c0,
    float* __restrict__ ws) {
  int* wsi = (int*)(ws + OFF_INT);
  if (blockIdx.x < 128) {
    int g = blockIdx.x * 256 + threadIdx.x;   // 0..32767
    int d = g >> 5, bk = g & 31;
    ws[OFF_HTN + g] = h0[(size_t)bk * Dd + d];   // transpose to [d][bk]
    ws[OFF_CB0 + g] = c0[g];                     // [32][1024] linear
  } else {
    int t = threadIdx.x;
    if (t < BKn) {
      ws[OFF_SC + t] = ((t & 3) == 0) ? 0.f : BIGf;
      wsi[IW + t] = words[t];
      wsi[IPREV + t] = t & 3;                    // identity gather for step 0
    }
    if (t < Bb) wsi[ISTOP + t] = 0;
    for (int i = t; i < 2 * Bb * Kk * Tt; i += 256) wsi[IBUFA + i] = 0;
  }
}

// gates partial GEMM. grid (32, 32): x = 128-col tile of f, y = d-chunk of 32.
__global__ __launch_bounds__(256) void gatesK(const float* __restrict__ Wx,
    const float* __restrict__ Wh, const float* __restrict__ E,
    const float* __restrict__ hTn, const int* __restrict__ wsi,
    float* __restrict__ Gp) {
  __shared__ float xs[GDC][BKn], hs[GDC][BKn];
  int tid = threadIdx.x;
  int d0 = blockIdx.y * GDC;
  {
    int bk = tid & 31, dq = tid >> 5;           // dq 0..7, 4 d each
    int w = wsi[IW + bk];
    int src = (bk & ~3) | wsi[IPREV + bk];
    const float* Erow = E + (size_t)w * Dd + d0;
#pragma unroll
    for (int k = 0; k < 4; k++) {
      int d = dq * 4 + k;
      xs[d][bk] = Erow[d];
      hs[d][bk] = hTn[(size_t)(d0 + d) * BKn + src];
    }
  }
  __syncthreads();
  int ct = tid & 31, bg = tid >> 5;             // 32 col-threads, 8 beam-groups
  int f0 = blockIdx.x * 128 + ct * 4;
  float acc[4][4];                               // [col][beam-in-group]
#pragma unroll
  for (int c = 0; c < 4; c++)
#pragma unroll
    for (int i = 0; i < 4; i++) acc[c][i] = 0.f;
#pragma unroll 4
  for (int d = 0; d < GDC; ++d) {
    float4 wx = *(const float4*)(Wx + (size_t)(d0 + d) * Ff + f0);
    float4 wh = *(const float4*)(Wh + (size_t)(d0 + d) * Ff + f0);
    float4 x4 = *(const float4*)&xs[d][bg * 4];
    float4 h4 = *(const float4*)&hs[d][bg * 4];
    float xv[4] = {x4.x, x4.y, x4.z, x4.w};
    float hv[4] = {h4.x, h4.y, h4.z, h4.w};
    float wxc[4] = {wx.x, wx.y, wx.z, wx.w};
    float whc[4] = {wh.x, wh.y, wh.z, wh.w};
#pragma unroll
    for (int c = 0; c < 4; c++)
#pragma unroll
      for (int i = 0; i < 4; i++)
        acc[c][i] = fmaf(xv[i], wxc[c], fmaf(hv[i], whc[c], acc[c][i]));
  }
#pragma unroll
  for (int i = 0; i < 4; i++) {
    int bk = bg * 4 + i;
    float4 o = {acc[0][i], acc[1][i], acc[2][i], acc[3][i]};
    *(float4*)(Gp + ((size_t)blockIdx.y * BKn + bk) * Ff + f0) = o;
  }
}

// reduce 32 gate partials + bias -> nonlinearity; gathers c by prev.
__global__ __launch_bounds__(256) void lstmK(const float* __restrict__ bvec,
    const float* __restrict__ Gp, const float* __restrict__ cPrev,
    const int* __restrict__ wsi, float* __restrict__ cNew,
    float* __restrict__ hTn) {
  __shared__ float part[4][128];
  int bk = blockIdx.x;
  int dcl = threadIdx.x & 127;
  int half = threadIdx.x >> 7;
  int dc = blockIdx.y * 128 + dcl;
  float s[4] = {0.f, 0.f, 0.f, 0.f};
#pragma unroll 4
  for (int dsl = 0; dsl < 16; dsl++) {
    int ds = half * 16 + dsl;
    const float* row = Gp + ((size_t)ds * BKn + bk) * Ff;
#pragma unroll
    for (int g = 0; g < 4; g++) s[g] += row[(size_t)g * Dd + dc];
  }
  if (half == 1) {
#pragma unroll
    for (int g = 0; g < 4; g++) part[g][dcl] = s[g];
  }
  __syncthreads();
  if (half == 0) {
    float gi = s[0] + part[0][dcl] + bvec[dc];
    float gf = s[1] + part[1][dcl] + bvec[Dd + dc];
    float gg = s[2] + part[2][dcl] + bvec[2 * Dd + dc];
    float go = s[3] + part[3][dcl] + bvec[3 * Dd + dc];
    int src = (bk & ~3) | wsi[IPREV + bk];
    float c = cPrev[(size_t)src * Dd + dc];
    float si = 1.f / (1.f + expf(-gi));
    float sf = 1.f / (1.f + expf(-gf));
    float so = 1.f / (1.f + expf(-go));
    float tg = tanhf(gg);
    float cn = sf * c + si * tg;
    float hn = so * tanhf(cn);
    cNew[(size_t)bk * Dd + dc] = cn;
    hTn[(size_t)dc * BKn + bk] = hn;
  }
}

// Per-wave-pipelined logits + chunk stats. grid 500 blocks x 256 thr (4 waves).
// Each wave owns a private d-quarter (256 d, 16 chunks of 16): it stages its
// own Wo/h chunks via global_load_lds (6 cp16/chunk, triple buffer, depth-2,
// per-wave counted vmcnt(12)) and consumes only its own buffers -> ZERO
// barriers in the chunk loop (no inter-wave convoy; R16's occupancy fix: 8
// waves/CU here vs 1.8 there). Thread tile 4 cols x 8 beams = 48B LDS per
// 32 FMA (1.5 B/FMA, 25% below R12). Cross-wave combine + stats at the end.
__global__ __launch_bounds__(256) void logitsAK(const float* __restrict__ Wo,
    const float* __restrict__ bo, const float* __restrict__ hTn,
    float* __restrict__ cs) {
  __shared__ float wb[4][3][LQC][LTW];   // 48 KB
  __shared__ float hb[4][3][LQC][BKn];   // 24 KB
  __shared__ float sd[BKn][LTW];         // 8 KB  (total 80 KB -> 2 blocks/CU)
  int tid = threadIdx.x;
  int q = tid >> 6;                   // wave = d-quarter 0..3
  int lane = tid & 63;
  int cg = lane & 15;                 // col group (4 cols)
  int bg = lane >> 4;                 // beam group (8 beams), 0..3
  size_t v0 = (size_t)blockIdx.x * LTW;
  int dq0 = q * 256;
  float acc[4][8];                    // [col][beam]
#pragma unroll
  for (int c = 0; c < 4; c++)
#pragma unroll
    for (int i = 0; i < 8; i++) acc[c][i] = 0.f;

  // bias: 1 VMEM per wave, issued FIRST (oldest outstanding, drains first)
  float4 b4 = *(const float4*)(bo + v0 + cg * 4);

  // per-wave stage of own-quarter chunk CH into buf B: 4 Wo cp16 + 2 h cp16
#define STAGE(CH, B)                                                          \
  {                                                                           \
    int d0_ = dq0 + (CH) * LQC;                                               \
    _Pragma("unroll") for (int i_ = 0; i_ < 4; i_++)                          \
      cp16(Wo + (size_t)(d0_ + i_ * 4 + (lane >> 4)) * Vv + v0 +              \
               (lane & 15) * 4,                                               \
           &wb[q][B][i_ * 4][0]);                                             \
    _Pragma("unroll") for (int j_ = 0; j_ < 2; j_++)                          \
      cp16(hTn + (size_t)(d0_ + j_ * 8 + (lane >> 3)) * BKn + (lane & 7) * 4, \
           &hb[q][B][j_ * 8][0]);                                             \
  }

  STAGE(0, 0)
  STAGE(1, 1)
  for (int k = 0; k < LQN; k++) {
    int b = k % 3;
    if (k + 2 < LQN) {
      STAGE(k + 2, (k + 2) % 3)
      asm volatile("s_waitcnt vmcnt(12)" ::: "memory");  // own chunk k landed
    } else if (k + 1 < LQN) {
      asm volatile("s_waitcnt vmcnt(6)" ::: "memory");
    } else {
      asm volatile("s_waitcnt vmcnt(0)" ::: "memory");
    }
    __builtin_amdgcn_sched_barrier(0);   // rule #18: pin LDS reads after wait
#pragma unroll 4
    for (int d = 0; d < LQC; d++) {
      float4 w4  = *(const float4*)&wb[q][b][d][cg * 4];
      float4 hlo = *(const float4*)&hb[q][b][d][bg * 8];
      float4 hhi = *(const float4*)&hb[q][b][d][bg * 8 + 4];
      float wv[4] = {w4.x, w4.y, w4.z, w4.w};
      float hv[8] = {hlo.x, hlo.y, hlo.z, hlo.w, hhi.x, hhi.y, hhi.z, hhi.w};
#pragma unroll
      for (int c = 0; c < 4; c++)
#pragma unroll
        for (int i = 0; i < 8; i++)
          acc[c][i] = fmaf(wv[c], hv[i], acc[c][i]);
    }
    // no barrier: wave consumes only its own buffers; vmcnt spacing governs reuse
  }
#undef STAGE

  // combine quarters in sd: q0 writes (+bias), q1..q3 accumulate sequentially
  float bb[4] = {b4.x, b4.y, b4.z, b4.w};
  if (q == 0) {
#pragma unroll
    for (int c = 0; c < 4; c++)
#pragma unroll
      for (int i = 0; i < 8; i++)
        sd[bg * 8 + i][cg * 4 + c] = acc[c][i] + bb[c];
  }
  __syncthreads();
#pragma unroll
  for (int qq = 1; qq < 4; qq++) {
    if (q == qq) {
#pragma unroll
      for (int c = 0; c < 4; c++)
#pragma unroll
        for (int i = 0; i < 8; i++)
          sd[bg * 8 + i][cg * 4 + c] += acc[c][i];
    }
    __syncthreads();
  }

  // stats: 4 waves x 8 beams = 32 beams, full 64-lane wave over 64 cols
  int i0 = (int)v0 + lane;
  for (int bb_ = 0; bb_ < 8; ++bb_) {
    int bk = q * 8 + bb_;
    float v0f = sd[bk][lane];
    float m = v0f;
    for (int off = 32; off; off >>= 1) m = fmaxf(m, __shfl_xor(m, off));
    float se = expf(v0f - m);
    for (int off = 32; off; off >>= 1) se += __shfl_xor(se, off);
    float tv[4]; int ti[4];
#pragma unroll
    for (int r = 0; r < 4; r++) { tv[r] = -FLT_MAX; ti[r] = 0x7fffffff; }
    ins4(v0f, i0, tv, ti);
    float ov[4]; int oi[4];
    merge_top4<32>(tv, ti, ov, oi);
    if (lane == 0) {
      float* p = cs + ((size_t)blockIdx.x * BKn + bk) * 12;
      p[0] = m; p[1] = se;
#pragma unroll
      for (int r = 0; r < 4; r++) { p[2 + r] = ov[r]; p[6 + r] = __int_as_float(oi[r]); }
    }
  }
}

// fused: per-beam online merge of 500 chunk stats -> lse + top4; then exact
// selection, EOS logic, buf ping-pong. One block of 1024 threads.
// Loads batched in groups of 4 chunks via explicit float4 register arrays.
__global__ __launch_bounds__(1024) void redSelK(float* __restrict__ ws, int step) {
  __shared__ float bt_s[BKn][8];
  __shared__ int s_tok[BKn], s_prevb[BKn];
  int* wsi = (int*)(ws + OFF_INT);
  const float* cs = ws + OFF_CS;
  int tid = threadIdx.x;
  int wv = tid >> 6, lane = tid & 63;
  {
    int half = lane >> 5, l32 = lane & 31;
    int bk = wv * 2 + half;                 // 16 waves x 2 halves = 32 beams
    float tv[4]; int ti[4];
#pragma unroll
    for (int r = 0; r < 4; r++) { tv[r] = -FLT_MAX; ti[r] = 0x7fffffff; }
    float M = -FLT_MAX, ls = 0.f;
    for (int g = 0; g < 4; g++) {           // 4 groups x 4 chunks = 16 chunks/lane
      float4 pa[4], pb[4], pc[4];
      bool vv[4];
#pragma unroll
      for (int j = 0; j < 4; j++) {
        int c = l32 + 32 * (g * 4 + j);
        vv[j] = c < NVCH;
        const float* p = cs + ((size_t)c * BKn + bk) * 12;
        if (vv[j]) {
          pa[j] = *(const float4*)p;        // {m, se, ov0, ov1}
          pb[j] = *(const float4*)(p + 4);  // {ov2, ov3, oi0, oi1}
          pc[j] = *(const float4*)(p + 8);  // {oi2, oi3, -, -}
        }
      }
#pragma unroll
      for (int j = 0; j < 4; j++) {
        if (vv[j]) {
          float cm = pa[j].x, csum = pa[j].y;
          if (cm > M) { ls *= expf(M - cm); M = cm; }   // ls==0 when M==-inf
          ls += csum * expf(cm - M);
          ins4(pa[j].z, __float_as_int(pb[j].z), tv, ti);
          ins4(pa[j].w, __float_as_int(pb[j].w), tv, ti);
          ins4(pb[j].x, __float_as_int(pc[j].x), tv, ti);
          ins4(pb[j].y, __float_as_int(pc[j].y), tv, ti);
        }
      }
    }
    for (int off = 16; off; off >>= 1) {
      float Mo = __shfl_xor(M, off), lso = __shfl_xor(ls, off);
      float Mn = fmaxf(M, Mo);
      ls = ls * expf(M - Mn) + lso * expf(Mo - Mn);
      M = Mn;
    }
    float lse = M + logf(ls);
    float ov[4]; int oi[4];
    merge_top4<16>(tv, ti, ov, oi);
    if (l32 == 0) {
#pragma unroll
      for (int r = 0; r < 4; r++) {
        bt_s[bk][r] = lse - ov[r];
        bt_s[bk][4 + r] = __int_as_float(oi[r]);
      }
    }
  }
  __syncthreads();
  if (tid < Bb) {
    int b = tid;
    int st = wsi[ISTOP + b];
    float sc[4];
#pragma unroll
    for (int k = 0; k < 4; k++) sc[k] = ws[OFF_SC + b * 4 + k];
    float cval[16]; int ctok[16];
#pragma unroll
    for (int kb = 0; kb < 4; kb++)
#pragma unroll
      for (int r = 0; r < 4; r++) {
        cval[kb * 4 + r] = bt_s[b * 4 + kb][r] + sc[kb];
        ctok[kb * 4 + r] = __float_as_int(bt_s[b * 4 + kb][4 + r]);
      }
    float selS[4]; int selW[4], prevK[4];
    int usedMask = 0;
#pragma unroll
    for (int r = 0; r < 4; r++) {
      int best = -1; float bv = FLT_MAX;
#pragma unroll
      for (int t = 0; t < 16; t++) {
        if (!((usedMask >> t) & 1) && cval[t] < bv) { bv = cval[t]; best = t; }
      }
      usedMask |= 1 << best;
      int tok = 0;
#pragma unroll
      for (int t = 0; t < 16; t++) if (t == best) tok = ctok[t];   // no runtime index
      selS[r] = bv; selW[r] = tok; prevK[r] = best >> 2;
    }
    bool eos[4];
#pragma unroll
    for (int r = 0; r < 4; r++) eos[r] = (selW[r] == EOSt);
    bool first = eos[0] && !st;
#pragma unroll
    for (int r = 0; r < 4; r++) if (eos[r] && !first && !st) selS[r] = EOSSf;
#pragma unroll
    for (int k = 0; k < 4; k++) {
      int tok = st ? PADt : (first ? EOSt : selW[k]);
      int pb  = st ? k : prevK[k];
      s_tok[b * 4 + k] = tok;
      s_prevb[b * 4 + k] = pb;
      if (!st) { ws[OFF_SC + b * 4 + k] = selS[k]; wsi[IW + b * 4 + k] = selW[k]; }
      wsi[IPREV + b * 4 + k] = prevK[k];
    }
    wsi[ISTOP + b] = (st || first) ? 1 : 0;
  }
  __syncthreads();
  if (tid < 512) {
    const int* br = wsi + (((step & 1) == 0) ? IBUFA : IBUFB);
    int* bw = wsi + (((step & 1) == 0) ? IBUFB : IBUFA);
    int bkk = tid >> 4, t = tid & 15;
    int pb = s_prevb[bkk];
    int src = ((bkk & ~3) | pb) * Tt + t;
    int val = br[src];
    if (t == step) val = s_tok[bkk];
    bw[tid] = val;
  }
}

// Output read as float32 by harness: tokens as float values, scores as floats.
__global__ __launch_bounds__(256) void outK(const float* __restrict__ ws,
                                            float* __restrict__ out) {
  const int* wsi = (const int*)(ws + OFF_INT);
  int g = blockIdx.x * 256 + threadIdx.x;
  if (g < Bb * Kk * Tt) {
    out[g] = (float)wsi[IBUFA + g];               // final buf in A after 16 steps
  } else if (g < Bb * Kk * Tt + BKn) {
    out[g] = ws[OFF_SC + (g - Bb * Kk * Tt)];
  }
}

} // namespace

extern "C" void kernel_launch(void* const* d_in, const int* in_sizes, int n_in,
                              void* d_out, int out_size, void* d_ws, size_t ws_size,
                              hipStream_t stream) {
  (void)in_sizes; (void)n_in; (void)out_size; (void)ws_size;
  const int*   words = (const int*)d_in[0];
  const float* h0 = (const float*)d_in[1];
  const float* c0 = (const float*)d_in[2];
  const float* E  = (const float*)d_in[3];
  const float* Wx = (const float*)d_in[4];
  const float* Wh = (const float*)d_in[5];
  const float* bv = (const float*)d_in[6];
  const float* Wo = (const float*)d_in[7];
  const float* bo = (const float*)d_in[8];
  float* ws = (float*)d_ws;
  float* hTn = ws + OFF_HTN;
  float* cb0 = ws + OFF_CB0;
  float* cb1 = ws + OFF_CB1;
  float* Gp  = ws + OFF_GP;
  float* cs  = ws + OFF_CS;
  int*   wsi = (int*)(ws + OFF_INT);

  initK<<<129, 256, 0, stream>>>(words, h0, c0, ws);
  for (int j = 0; j < Tt; j++) {
    float* cPrev = (j & 1) ? cb1 : cb0;
    float* cNext = (j & 1) ? cb0 : cb1;
    gatesK<<<dim3(32, GDS), 256, 0, stream>>>(Wx, Wh, E, hTn, wsi, Gp);
    lstmK<<<dim3(32, 8), 256, 0, stream>>>(bv, Gp, cPrev, wsi, cNext, hTn);
    logitsAK<<<LNB, 256, 0, stream>>>(Wo, bo, hTn, cs);
    redSelK<<<1, 1024, 0, stream>>>(ws, j);
  }
  outK<<<3, 256, 0, stream>>>(ws, (float*)d_out);
}

// Round 19
// 1663.610 us; speedup vs baseline: 1.8273x; 1.0390x over previous
//
#include <hip/hip_runtime.h>
#include <math.h>
#include <float.h>

namespace {

constexpr int Bb = 8, Kk = 4, BKn = 32, Dd = 1024, Ff = 4096, Vv = 32000, Tt = 16;
constexpr int GDS = 8;                   // gate partial splits (8 x 128 d)
constexpr int LTW = 64;                  // logits cols per block
constexpr int LNB = Vv / LTW;            // 500 blocks
constexpr int LQC = 16;                  // logits d per chunk (per quarter)
constexpr int LQN = 16;                  // logits chunks per quarter
constexpr int NVCH = LNB;                // 500 chunk-stat rows
constexpr int EOSt = 2, PADt = 0;
constexpr float BIGf = 1e9f, EOSSf = 1000.0f;

// ---- workspace layout (float indices) ----
constexpr size_t OFF_HTN = 0;                                   // hTn [1024][32]
constexpr size_t OFF_CB0 = OFF_HTN + (size_t)Dd * BKn;          // c ping [32][1024]
constexpr size_t OFF_CB1 = OFF_CB0 + (size_t)BKn * Dd;          // c pong
constexpr size_t OFF_GP  = OFF_CB1 + (size_t)BKn * Dd;          // gate partials [8][32][4096]
constexpr size_t OFF_CS  = OFF_GP  + (size_t)GDS * BKn * Ff;    // chunk stats [500][32][12]
constexpr size_t OFF_SC  = OFF_CS  + (size_t)NVCH * BKn * 12;   // scores [32]
constexpr size_t OFF_INT = OFF_SC  + BKn;                       // int region
constexpr int IW = 0, ISTOP = 32, IPREV = 40, IBUFA = 72, IBUFB = IBUFA + Bb * Kk * Tt;

__device__ __forceinline__ void cp16(const float* g, float* l) {
  __builtin_amdgcn_global_load_lds(
      (const __attribute__((address_space(1))) void*)g,
      (__attribute__((address_space(3))) void*)l, 16, 0, 0);
}

__device__ inline void ins4(float v, int id, float tv[4], int ti[4]) {
#pragma unroll
  for (int r = 0; r < 4; r++) {
    bool better = (v > tv[r]) || (v == tv[r] && id < ti[r]);
    if (better) { float fv = tv[r]; int fi = ti[r]; tv[r] = v; ti[r] = id; v = fv; id = fi; }
  }
}

// merge per-lane sorted top-4 into group-global top-4. STARTOFF=32 -> 64-lane wave,
// STARTOFF=16 -> independent 32-lane halves.
template <int STARTOFF>
__device__ inline void merge_top4(float tv[4], int ti[4], float ov[4], int oi[4]) {
#pragma unroll
  for (int r = 0; r < 4; r++) {
    float hv = tv[0]; int hi = ti[0];
    float m = hv;
    for (int off = STARTOFF; off; off >>= 1) m = fmaxf(m, __shfl_xor(m, off));
    int c = (hv == m) ? hi : 0x7fffffff;
    for (int off = STARTOFF; off; off >>= 1) c = min(c, __shfl_xor(c, off));
    if (hv == m && hi == c) {   // this lane's head won: pop
      tv[0] = tv[1]; ti[0] = ti[1];
      tv[1] = tv[2]; ti[1] = ti[2];
      tv[2] = tv[3]; ti[2] = ti[3];
      tv[3] = -FLT_MAX; ti[3] = 0x7fffffff;
    }
    ov[r] = m; oi[r] = c;
  }
}

__global__ __launch_bounds__(256) void initK(const int* __restrict__ words,
    const float* __restrict__ h0, const float* __restrict__ c0,
    float* __restrict__ ws) {
  int* wsi = (int*)(ws + OFF_INT);
  if (blockIdx.x < 128) {
    int g = blockIdx.x * 256 + threadIdx.x;   // 0..32767
    int d = g >> 5, bk = g & 31;
    ws[OFF_HTN + g] = h0[(size_t)bk * Dd + d];   // transpose to [d][bk]
    ws[OFF_CB0 + g] = c0[g];                     // [32][1024] linear
  } else {
    int t = threadIdx.x;
    if (t < BKn) {
      ws[OFF_SC + t] = ((t & 3) == 0) ? 0.f : BIGf;
      wsi[IW + t] = words[t];
      wsi[IPREV + t] = t & 3;                    // identity gather for step 0
    }
    if (t < Bb) wsi[ISTOP + t] = 0;
    for (int i = t; i < 2 * Bb * Kk * Tt; i += 256) wsi[IBUFA + i] = 0;
  }
}

// Per-wave-pipelined gates partial GEMM (R18 logits pattern applied to gates).
// grid (64, 8): x = 64-col f-tile, y = 128-d split. 256 thr = 4 waves; wave q
// owns local d [q*32, q*32+32) in 8 chunks of 4 d. Wx/Wh chunks (1KB each)
// staged per-wave via global_load_lds, triple buffer depth-2, vmcnt(4) --
// NO barriers in the chunk loop. x/h staged once per block in LDS.
// Thread tile 4 f-cols x 8 beams. 4-phase combine -> Gp[8][32][4096].
__global__ __launch_bounds__(256) void gatesAK(const float* __restrict__ Wx,
    const float* __restrict__ Wh, const float* __restrict__ E,
    const float* __restrict__ hTn, const int* __restrict__ wsi,
    float* __restrict__ Gp) {
  __shared__ float wxb[4][3][4][64];   // 12 KB
  __shared__ float whb[4][3][4][64];   // 12 KB
  __shared__ float xs[128][BKn];       // 16 KB
  __shared__ float hs[128][BKn];       // 16 KB
  __shared__ float sd[BKn][64];        // 8 KB   (total 64 KB -> 2 blocks/CU)
  int tid = threadIdx.x;
  int q = tid >> 6;                    // wave 0..3
  int lane = tid & 63;
  int cg = lane & 15;                  // col group (4 f-cols)
  int bg = lane >> 4;                  // beam group (8 beams), 0..3
  int f0 = blockIdx.x * 64;
  int dblk0 = blockIdx.y * 128;

  {  // stage x = E[w], h = hTn[:, src] for this block's 128 d
    int bk = tid & 31, dq = tid >> 5;  // 8 groups x 16 d
    int w = wsi[IW + bk];
    int src = (bk & ~3) | wsi[IPREV + bk];
    const float* Erow = E + (size_t)w * Dd + dblk0;
#pragma unroll
    for (int k = 0; k < 16; k++) {
      int d = dq * 16 + k;
      xs[d][bk] = Erow[d];
      hs[d][bk] = hTn[(size_t)(dblk0 + d) * BKn + src];
    }
  }
  __syncthreads();   // drains vmcnt; staging counts start clean

  float acc[4][8];   // [col][beam]
#pragma unroll
  for (int c = 0; c < 4; c++)
#pragma unroll
    for (int i = 0; i < 8; i++) acc[c][i] = 0.f;

  // stage own chunk CH (4 d x 64 f of Wx and Wh) into buf B: 2 cp16/wave
#define STAGE(CH, B)                                                          \
  {                                                                           \
    int gd_ = dblk0 + q * 32 + (CH) * 4 + (lane >> 4);                        \
    cp16(Wx + (size_t)gd_ * Ff + f0 + (lane & 15) * 4, &wxb[q][B][0][0]);     \
    cp16(Wh + (size_t)gd_ * Ff + f0 + (lane & 15) * 4, &whb[q][B][0][0]);     \
  }

  STAGE(0, 0)
  STAGE(1, 1)
  for (int k = 0; k < 8; k++) {
    int b = k % 3;
    if (k + 2 < 8) {
      STAGE(k + 2, (k + 2) % 3)
      asm volatile("s_waitcnt vmcnt(4)" ::: "memory");  // own chunk k landed
    } else if (k + 1 < 8) {
      asm volatile("s_waitcnt vmcnt(2)" ::: "memory");
    } else {
      asm volatile("s_waitcnt vmcnt(0)" ::: "memory");
    }
    __builtin_amdgcn_sched_barrier(0);   // rule #18
    int ldb = q * 32 + k * 4;
#pragma unroll
    for (int d = 0; d < 4; d++) {
      float4 wx4 = *(const float4*)&wxb[q][b][d][cg * 4];
      float4 wh4 = *(const float4*)&whb[q][b][d][cg * 4];
      float4 xlo = *(const float4*)&xs[ldb + d][bg * 8];
      float4 xhi = *(const float4*)&xs[ldb + d][bg * 8 + 4];
      float4 hlo = *(const float4*)&hs[ldb + d][bg * 8];
      float4 hhi = *(const float4*)&hs[ldb + d][bg * 8 + 4];
      float wxc[4] = {wx4.x, wx4.y, wx4.z, wx4.w};
      float whc[4] = {wh4.x, wh4.y, wh4.z, wh4.w};
      float xv[8] = {xlo.x, xlo.y, xlo.z, xlo.w, xhi.x, xhi.y, xhi.z, xhi.w};
      float hv[8] = {hlo.x, hlo.y, hlo.z, hlo.w, hhi.x, hhi.y, hhi.z, hhi.w};
#pragma unroll
      for (int c = 0; c < 4; c++)
#pragma unroll
        for (int i = 0; i < 8; i++)
          acc[c][i] = fmaf(xv[i], wxc[c], fmaf(hv[i], whc[c], acc[c][i]));
    }
  }
#undef STAGE

  // combine 4 wave-partials in sd
  if (q == 0) {
#pragma unroll
    for (int c = 0; c < 4; c++)
#pragma unroll
      for (int i = 0; i < 8; i++)
        sd[bg * 8 + i][cg * 4 + c] = acc[c][i];
  }
  __syncthreads();
#pragma unroll
  for (int qq = 1; qq < 4; qq++) {
    if (q == qq) {
#pragma unroll
      for (int c = 0; c < 4; c++)
#pragma unroll
        for (int i = 0; i < 8; i++)
          sd[bg * 8 + i][cg * 4 + c] += acc[c][i];
    }
    __syncthreads();
  }

  // write Gp[blockIdx.y][bk][f0..f0+64)
  {
    int row = tid >> 3, c8 = tid & 7;
    float* dst = Gp + ((size_t)blockIdx.y * BKn + row) * Ff + f0 + c8 * 8;
    *(float4*)dst       = *(const float4*)&sd[row][c8 * 8];
    *(float4*)(dst + 4) = *(const float4*)&sd[row][c8 * 8 + 4];
  }
}

// reduce 8 gate partials + bias -> nonlinearity; gathers c by prev.
__global__ __launch_bounds__(256) void lstmK(const float* __restrict__ bvec,
    const float* __restrict__ Gp, const float* __restrict__ cPrev,
    const int* __restrict__ wsi, float* __restrict__ cNew,
    float* __restrict__ hTn) {
  __shared__ float part[4][128];
  int bk = blockIdx.x;
  int dcl = threadIdx.x & 127;
  int half = threadIdx.x >> 7;
  int dc = blockIdx.y * 128 + dcl;
  float s[4] = {0.f, 0.f, 0.f, 0.f};
#pragma unroll
  for (int dsl = 0; dsl < 4; dsl++) {
    int ds = half * 4 + dsl;
    const float* row = Gp + ((size_t)ds * BKn + bk) * Ff;
#pragma unroll
    for (int g = 0; g < 4; g++) s[g] += row[(size_t)g * Dd + dc];
  }
  if (half == 1) {
#pragma unroll
    for (int g = 0; g < 4; g++) part[g][dcl] = s[g];
  }
  __syncthreads();
  if (half == 0) {
    float gi = s[0] + part[0][dcl] + bvec[dc];
    float gf = s[1] + part[1][dcl] + bvec[Dd + dc];
    float gg = s[2] + part[2][dcl] + bvec[2 * Dd + dc];
    float go = s[3] + part[3][dcl] + bvec[3 * Dd + dc];
    int src = (bk & ~3) | wsi[IPREV + bk];
    float c = cPrev[(size_t)src * Dd + dc];
    float si = 1.f / (1.f + expf(-gi));
    float sf = 1.f / (1.f + expf(-gf));
    float so = 1.f / (1.f + expf(-go));
    float tg = tanhf(gg);
    float cn = sf * c + si * tg;
    float hn = so * tanhf(cn);
    cNew[(size_t)bk * Dd + dc] = cn;
    hTn[(size_t)dc * BKn + bk] = hn;
  }
}

// Per-wave-pipelined logits + chunk stats (R18, unchanged: best measured).
__global__ __launch_bounds__(256) void logitsAK(const float* __restrict__ Wo,
    const float* __restrict__ bo, const float* __restrict__ hTn,
    float* __restrict__ cs) {
  __shared__ float wb[4][3][LQC][LTW];   // 48 KB
  __shared__ float hb[4][3][LQC][BKn];   // 24 KB
  __shared__ float sd[BKn][LTW];         // 8 KB  (total 80 KB -> 2 blocks/CU)
  int tid = threadIdx.x;
  int q = tid >> 6;                   // wave = d-quarter 0..3
  int lane = tid & 63;
  int cg = lane & 15;                 // col group (4 cols)
  int bg = lane >> 4;                 // beam group (8 beams), 0..3
  size_t v0 = (size_t)blockIdx.x * LTW;
  int dq0 = q * 256;
  float acc[4][8];                    // [col][beam]
#pragma unroll
  for (int c = 0; c < 4; c++)
#pragma unroll
    for (int i = 0; i < 8; i++) acc[c][i] = 0.f;

  // bias: 1 VMEM per wave, issued FIRST (oldest outstanding, drains first)
  float4 b4 = *(const float4*)(bo + v0 + cg * 4);

  // per-wave stage of own-quarter chunk CH into buf B: 4 Wo cp16 + 2 h cp16
#define STAGE(CH, B)                                                          \
  {                                                                           \
    int d0_ = dq0 + (CH) * LQC;                                               \
    _Pragma("unroll") for (int i_ = 0; i_ < 4; i_++)                          \
      cp16(Wo + (size_t)(d0_ + i_ * 4 + (lane >> 4)) * Vv + v0 +              \
               (lane & 15) * 4,                                               \
           &wb[q][B][i_ * 4][0]);                                             \
    _Pragma("unroll") for (int j_ = 0; j_ < 2; j_++)                          \
      cp16(hTn + (size_t)(d0_ + j_ * 8 + (lane >> 3)) * BKn + (lane & 7) * 4, \
           &hb[q][B][j_ * 8][0]);                                             \
  }

  STAGE(0, 0)
  STAGE(1, 1)
  for (int k = 0; k < LQN; k++) {
    int b = k % 3;
    if (k + 2 < LQN) {
      STAGE(k + 2, (k + 2) % 3)
      asm volatile("s_waitcnt vmcnt(12)" ::: "memory");  // own chunk k landed
    } else if (k + 1 < LQN) {
      asm volatile("s_waitcnt vmcnt(6)" ::: "memory");
    } else {
      asm volatile("s_waitcnt vmcnt(0)" ::: "memory");
    }
    __builtin_amdgcn_sched_barrier(0);   // rule #18: pin LDS reads after wait
#pragma unroll 4
    for (int d = 0; d < LQC; d++) {
      float4 w4  = *(const float4*)&wb[q][b][d][cg * 4];
      float4 hlo = *(const float4*)&hb[q][b][d][bg * 8];
      float4 hhi = *(const float4*)&hb[q][b][d][bg * 8 + 4];
      float wv[4] = {w4.x, w4.y, w4.z, w4.w};
      float hv[8] = {hlo.x, hlo.y, hlo.z, hlo.w, hhi.x, hhi.y, hhi.z, hhi.w};
#pragma unroll
      for (int c = 0; c < 4; c++)
#pragma unroll
        for (int i = 0; i < 8; i++)
          acc[c][i] = fmaf(wv[c], hv[i], acc[c][i]);
    }
    // no barrier: wave consumes only its own buffers; vmcnt spacing governs reuse
  }
#undef STAGE

  // combine quarters in sd: q0 writes (+bias), q1..q3 accumulate sequentially
  float bb[4] = {b4.x, b4.y, b4.z, b4.w};
  if (q == 0) {
#pragma unroll
    for (int c = 0; c < 4; c++)
#pragma unroll
      for (int i = 0; i < 8; i++)
        sd[bg * 8 + i][cg * 4 + c] = acc[c][i] + bb[c];
  }
  __syncthreads();
#pragma unroll
  for (int qq = 1; qq < 4; qq++) {
    if (q == qq) {
#pragma unroll
      for (int c = 0; c < 4; c++)
#pragma unroll
        for (int i = 0; i < 8; i++)
          sd[bg * 8 + i][cg * 4 + c] += acc[c][i];
    }
    __syncthreads();
  }

  // stats: 4 waves x 8 beams = 32 beams, full 64-lane wave over 64 cols
  int i0 = (int)v0 + lane;
  for (int bb_ = 0; bb_ < 8; ++bb_) {
    int bk = q * 8 + bb_;
    float v0f = sd[bk][lane];
    float m = v0f;
    for (int off = 32; off; off >>= 1) m = fmaxf(m, __shfl_xor(m, off));
    float se = expf(v0f - m);
    for (int off = 32; off; off >>= 1) se += __shfl_xor(se, off);
    float tv[4]; int ti[4];
#pragma unroll
    for (int r = 0; r < 4; r++) { tv[r] = -FLT_MAX; ti[r] = 0x7fffffff; }
    ins4(v0f, i0, tv, ti);
    float ov[4]; int oi[4];
    merge_top4<32>(tv, ti, ov, oi);
    if (lane == 0) {
      float* p = cs + ((size_t)blockIdx.x * BKn + bk) * 12;
      p[0] = m; p[1] = se;
#pragma unroll
      for (int r = 0; r < 4; r++) { p[2 + r] = ov[r]; p[6 + r] = __int_as_float(oi[r]); }
    }
  }
}

// fused: per-beam online merge of 500 chunk stats -> lse + top4; then exact
// selection, EOS logic, buf ping-pong. One block of 1024 threads.
__global__ __launch_bounds__(1024) void redSelK(float* __restrict__ ws, int step) {
  __shared__ float bt_s[BKn][8];
  __shared__ int s_tok[BKn], s_prevb[BKn];
  int* wsi = (int*)(ws + OFF_INT);
  const float* cs = ws + OFF_CS;
  int tid = threadIdx.x;
  int wv = tid >> 6, lane = tid & 63;
  {
    int half = lane >> 5, l32 = lane & 31;
    int bk = wv * 2 + half;                 // 16 waves x 2 halves = 32 beams
    float tv[4]; int ti[4];
#pragma unroll
    for (int r = 0; r < 4; r++) { tv[r] = -FLT_MAX; ti[r] = 0x7fffffff; }
    float M = -FLT_MAX, ls = 0.f;
    for (int g = 0; g < 4; g++) {           // 4 groups x 4 chunks = 16 chunks/lane
      float4 pa[4], pb[4], pc[4];
      bool vv[4];
#pragma unroll
      for (int j = 0; j < 4; j++) {
        int c = l32 + 32 * (g * 4 + j);
        vv[j] = c < NVCH;
        const float* p = cs + ((size_t)c * BKn + bk) * 12;
        if (vv[j]) {
          pa[j] = *(const float4*)p;        // {m, se, ov0, ov1}
          pb[j] = *(const float4*)(p + 4);  // {ov2, ov3, oi0, oi1}
          pc[j] = *(const float4*)(p + 8);  // {oi2, oi3, -, -}
        }
      }
#pragma unroll
      for (int j = 0; j < 4; j++) {
        if (vv[j]) {
          float cm = pa[j].x, csum = pa[j].y;
          if (cm > M) { ls *= expf(M - cm); M = cm; }   // ls==0 when M==-inf
          ls += csum * expf(cm - M);
          ins4(pa[j].z, __float_as_int(pb[j].z), tv, ti);
          ins4(pa[j].w, __float_as_int(pb[j].w), tv, ti);
          ins4(pb[j].x, __float_as_int(pc[j].x), tv, ti);
          ins4(pb[j].y, __float_as_int(pc[j].y), tv, ti);
        }
      }
    }
    for (int off = 16; off; off >>= 1) {
      float Mo = __shfl_xor(M, off), lso = __shfl_xor(ls, off);
      float Mn = fmaxf(M, Mo);
      ls = ls * expf(M - Mn) + lso * expf(Mo - Mn);
      M = Mn;
    }
    float lse = M + logf(ls);
    float ov[4]; int oi[4];
    merge_top4<16>(tv, ti, ov, oi);
    if (l32 == 0) {
#pragma unroll
      for (int r = 0; r < 4; r++) {
        bt_s[bk][r] = lse - ov[r];
        bt_s[bk][4 + r] = __int_as_float(oi[r]);
      }
    }
  }
  __syncthreads();
  if (tid < Bb) {
    int b = tid;
    int st = wsi[ISTOP + b];
    float sc[4];
#pragma unroll
    for (int k = 0; k < 4; k++) sc[k] = ws[OFF_SC + b * 4 + k];
    float cval[16]; int ctok[16];
#pragma unroll
    for (int kb = 0; kb < 4; kb++)
#pragma unroll
      for (int r = 0; r < 4; r++) {
        cval[kb * 4 + r] = bt_s[b * 4 + kb][r] + sc[kb];
        ctok[kb * 4 + r] = __float_as_int(bt_s[b * 4 + kb][4 + r]);
      }
    float selS[4]; int selW[4], prevK[4];
    int usedMask = 0;
#pragma unroll
    for (int r = 0; r < 4; r++) {
      int best = -1; float bv = FLT_MAX;
#pragma unroll
      for (int t = 0; t < 16; t++) {
        if (!((usedMask >> t) & 1) && cval[t] < bv) { bv = cval[t]; best = t; }
      }
      usedMask |= 1 << best;
      int tok = 0;
#pragma unroll
      for (int t = 0; t < 16; t++) if (t == best) tok = ctok[t];   // no runtime index
      selS[r] = bv; selW[r] = tok; prevK[r] = best >> 2;
    }
    bool eos[4];
#pragma unroll
    for (int r = 0; r < 4; r++) eos[r] = (selW[r] == EOSt);
    bool first = eos[0] && !st;
#pragma unroll
    for (int r = 0; r < 4; r++) if (eos[r] && !first && !st) selS[r] = EOSSf;
#pragma unroll
    for (int k = 0; k < 4; k++) {
      int tok = st ? PADt : (first ? EOSt : selW[k]);
      int pb  = st ? k : prevK[k];
      s_tok[b * 4 + k] = tok;
      s_prevb[b * 4 + k] = pb;
      if (!st) { ws[OFF_SC + b * 4 + k] = selS[k]; wsi[IW + b * 4 + k] = selW[k]; }
      wsi[IPREV + b * 4 + k] = prevK[k];
    }
    wsi[ISTOP + b] = (st || first) ? 1 : 0;
  }
  __syncthreads();
  if (tid < 512) {
    const int* br = wsi + (((step & 1) == 0) ? IBUFA : IBUFB);
    int* bw = wsi + (((step & 1) == 0) ? IBUFB : IBUFA);
    int bkk = tid >> 4, t = tid & 15;
    int pb = s_prevb[bkk];
    int src = ((bkk & ~3) | pb) * Tt + t;
    int val = br[src];
    if (t == step) val = s_tok[bkk];
    bw[tid] = val;
  }
}

// Output read as float32 by harness: tokens as float values, scores as floats.
__global__ __launch_bounds__(256) void outK(const float* __restrict__ ws,
                                            float* __restrict__ out) {
  const int* wsi = (const int*)(ws + OFF_INT);
  int g = blockIdx.x * 256 + threadIdx.x;
  if (g < Bb * Kk * Tt) {
    out[g] = (float)wsi[IBUFA + g];               // final buf in A after 16 steps
  } else if (g < Bb * Kk * Tt + BKn) {
    out[g] = ws[OFF_SC + (g - Bb * Kk * Tt)];
  }
}

} // namespace

extern "C" void kernel_launch(void* const* d_in, const int* in_sizes, int n_in,
                              void* d_out, int out_size, void* d_ws, size_t ws_size,
                              hipStream_t stream) {
  (void)in_sizes; (void)n_in; (void)out_size; (void)ws_size;
  const int*   words = (const int*)d_in[0];
  const float* h0 = (const float*)d_in[1];
  const float* c0 = (const float*)d_in[2];
  const float* E  = (const float*)d_in[3];
  const float* Wx = (const float*)d_in[4];
  const float* Wh = (const float*)d_in[5];
  const float* bv = (const float*)d_in[6];
  const float* Wo = (const float*)d_in[7];
  const float* bo = (const float*)d_in[8];
  float* ws = (float*)d_ws;
  float* hTn = ws + OFF_HTN;
  float* cb0 = ws + OFF_CB0;
  float* cb1 = ws + OFF_CB1;
  float* Gp  = ws + OFF_GP;
  float* cs  = ws + OFF_CS;
  int*   wsi = (int*)(ws + OFF_INT);

  initK<<<129, 256, 0, stream>>>(words, h0, c0, ws);
  for (int j = 0; j < Tt; j++) {
    float* cPrev = (j & 1) ? cb1 : cb0;
    float* cNext = (j & 1) ? cb0 : cb1;
    gatesAK<<<dim3(64, GDS), 256, 0, stream>>>(Wx, Wh, E, hTn, wsi, Gp);
    lstmK<<<dim3(32, 8), 256, 0, stream>>>(bv, Gp, cPrev, wsi, cNext, hTn);
    logitsAK<<<LNB, 256, 0, stream>>>(Wo, bo, hTn, cs);
    redSelK<<<1, 1024, 0, stream>>>(ws, j);
  }
  outK<<<3, 256, 0, stream>>>(ws, (float*)d_out);
}